// Round 9
// baseline (351.359 us; speedup 1.0000x reference)
//
#include <hip/hip_runtime.h>
#include <hip/hip_bf16.h>
#include <math.h>

#define NNODES 50000
#define NEDGES 800000
#define CHUNKS (NEDGES / 32)     // 25000 chunks of 32 CSR-ordered edges
#define NBLK 256
#define GWAVES (NBLK * 16)       // persistent waves

using short8 = __attribute__((ext_vector_type(8))) short;   // 8 bf16 = 4 VGPRs
using f32x4  = __attribute__((ext_vector_type(4))) float;
using f32x16 = __attribute__((ext_vector_type(16))) float;  // 32x32 MFMA acc
using u32x4  = __attribute__((ext_vector_type(4))) unsigned;

// fp32 -> bf16 RNE
__device__ __forceinline__ short f2b(float v) {
    return __builtin_bit_cast(short, __float2bfloat16(v));
}
// pack 2 fp32 -> 1 dword of 2 bf16 (lo = a)
__device__ __forceinline__ unsigned cvt2(float a, float b) {
    return (unsigned)(unsigned short)f2b(a) | ((unsigned)(unsigned short)f2b(b) << 16);
}
// order-preserving float->uint for atomicMax; 0 = "empty" sentinel
__device__ __forceinline__ unsigned encf(float v) {
    unsigned u = __builtin_bit_cast(unsigned, v);
    return (u & 0x80000000u) ? ~u : (u | 0x80000000u);
}

// ---- merged prep: x->bf16, W pack, CSR count ----
__global__ void prep_all(const float* __restrict__ x, short* __restrict__ xb,
                         const float* __restrict__ W1, const float* __restrict__ W2,
                         short* __restrict__ wpk, const int* __restrict__ ei,
                         unsigned* __restrict__ cnt)
{
    int b = blockIdx.x;
    if (b < 3125) {                       // x -> bf16 (800000 float4 groups)
        int i = b * 256 + threadIdx.x;
        float4 v = reinterpret_cast<const float4*>(x)[i];
        short4 o;
        o.x = f2b(v.x); o.y = f2b(v.y); o.z = f2b(v.z); o.w = f2b(v.w);
        reinterpret_cast<short4*>(xb)[i] = o;
    } else if (b < 6250) {                // CSR degree count
        int e = (b - 3125) * 256 + threadIdx.x;
        atomicAdd(&cnt[ei[e]], 1u);
    } else {                              // weight pack (32x32x16 A-frag order)
        int i = (b - 6250) * 256 + threadIdx.x;
        if (i < 40960) {                  // W1 [k<160][n<256]
            int k = i >> 8, n = i & 255;
            int lane = (n & 31) + (((k >> 3) & 1) << 5);
            wpk[(((n >> 5) * 10 + (k >> 4)) * 64 + lane) * 8 + (k & 7)] = f2b(W1[i]);
        }
        if (i < 16384) {                  // W2 [k<256][n<64]
            int k = i >> 6, n = i & 63;
            int lane = (n & 31) + (((k >> 3) & 1) << 5);
            wpk[40960 + (((n >> 5) * 16 + (k >> 4)) * 64 + lane) * 8 + (k & 7)] = f2b(W2[i]);
        }
    }
}

// ---- CSR scan/place (proven) ----
__global__ __launch_bounds__(1024)
void csr_scan1(const unsigned* __restrict__ cnt, unsigned* __restrict__ offs,
               unsigned* __restrict__ bsum) {
    __shared__ unsigned sbuf[1024];
    int t = threadIdx.x, i = blockIdx.x * 1024 + t;
    unsigned v = (i < NNODES) ? cnt[i] : 0u;
    sbuf[t] = v;
    __syncthreads();
    for (int off = 1; off < 1024; off <<= 1) {
        unsigned add = (t >= off) ? sbuf[t - off] : 0u;
        __syncthreads();
        sbuf[t] += add;
        __syncthreads();
    }
    if (i < NNODES) offs[i] = sbuf[t];
    if (t == 1023) bsum[blockIdx.x] = sbuf[1023];
}

__global__ void csr_scan2(unsigned* __restrict__ bsum) {
    int t = threadIdx.x;
    unsigned v = (t < 49) ? bsum[t] : 0u;
    unsigned orig = v;
    for (int off = 1; off < 64; off <<= 1) {
        unsigned n = __shfl_up(v, off, 64);
        if (t >= off) v += n;
    }
    if (t < 49) bsum[t] = v - orig;
}

__global__ __launch_bounds__(1024)
void csr_scan3(const unsigned* __restrict__ cnt, unsigned* __restrict__ offs,
               const unsigned* __restrict__ bsum) {
    int i = blockIdx.x * 1024 + threadIdx.x;
    if (i < NNODES)       offs[i] = offs[i] - cnt[i] + bsum[blockIdx.x];
    else if (i == NNODES) offs[i] = NEDGES;
}

__global__ void csr_place(const int* __restrict__ ei, const unsigned* __restrict__ offs,
                          unsigned* __restrict__ cur, unsigned* __restrict__ elist) {
    int e = blockIdx.x * 256 + threadIdx.x;
    if (e < NEDGES) {
        int r = ei[e];
        unsigned p = offs[r] + atomicAdd(&cur[r], 1u);
        elist[p] = (unsigned)e;
    }
}

// ---- main: CSR-ordered chunks, fused MLP + segmented-max aggregation ----
__global__ __launch_bounds__(1024, 4)
void edgeconv_main(const short* __restrict__ xb, const int* __restrict__ ei,
                   const float* __restrict__ ea, const short* __restrict__ wpk,
                   const float* __restrict__ b1, const float* __restrict__ b2,
                   const unsigned* __restrict__ elist,
                   float* __restrict__ outbuf, unsigned* __restrict__ aggenc)
{
    __shared__ short wlds[57344];        // 112 KB: W1 frags (80K) + W2 frags (32K)

    for (int i = threadIdx.x; i < 7168; i += 1024)
        reinterpret_cast<short8*>(wlds)[i] = reinterpret_cast<const short8*>(wpk)[i];
    __syncthreads();                     // only block-wide barrier

    const short* w1s = wlds;
    const short* w2s = wlds + 40960;
    const int lane = threadIdx.x & 63;
    const int wave = threadIdx.x >> 6;
    const int l32 = lane & 31, hi = lane >> 5;
    const int gw = blockIdx.x * 16 + wave;

    // prime the index pipeline for the first chunk
    int eo = 0, r = 0, cc = 0;
    if (gw < CHUNKS) {
        eo = (int)elist[gw * 32 + l32];
        r  = ei[eo];
        cc = ei[NEDGES + eo];
    }

    for (int c = gw; c < CHUNKS; c += GWAVES) {
        // ---- prefetch next chunk's indices (latency hidden under compute) ----
        int cn = c + GWAVES;
        int eo_n = 0, r_n = 0, cc_n = 0;
        if (cn < CHUNKS) {
            eo_n = (int)elist[cn * 32 + l32];
            r_n  = ei[eo_n];
            cc_n = ei[NEDGES + eo_n];
        }

        // ---- gather B-fragments: k = ks*16 + hi*8 + j (rows sorted -> L1 hits) ----
        short8 fx[10];
        #pragma unroll
        for (int ks = 0; ks < 4; ++ks)
            fx[ks] = *reinterpret_cast<const short8*>(xb + r * 64 + ks * 16 + hi * 8);
        #pragma unroll
        for (int ks = 0; ks < 4; ++ks)
            fx[4 + ks] = *reinterpret_cast<const short8*>(xb + cc * 64 + ks * 16 + hi * 8);
        #pragma unroll
        for (int ks = 0; ks < 2; ++ks) {
            const float4* p = reinterpret_cast<const float4*>(ea + (size_t)eo * 32 + ks * 16 + hi * 8);
            float4 a = p[0], b = p[1];
            u32x4 uu;
            uu[0] = cvt2(a.x, a.y); uu[1] = cvt2(a.z, a.w);
            uu[2] = cvt2(b.x, b.y); uu[3] = cvt2(b.z, b.w);
            fx[8 + ks] = __builtin_bit_cast(short8, uu);
        }

        // ---- acc2 init = b2 ----
        f32x16 acc2[2];
        #pragma unroll
        for (int t2 = 0; t2 < 2; ++t2)
            #pragma unroll
            for (int g = 0; g < 4; ++g) {
                float4 bb = *reinterpret_cast<const float4*>(b2 + t2 * 32 + g * 8 + hi * 4);
                acc2[t2][g * 4 + 0] = bb.x; acc2[t2][g * 4 + 1] = bb.y;
                acc2[t2][g * 4 + 2] = bb.z; acc2[t2][g * 4 + 3] = bb.w;
            }

        #pragma unroll 1
        for (int t = 0; t < 8; ++t) {    // 8 H-tiles of 32 cols
            f32x16 acc1;
            #pragma unroll
            for (int g = 0; g < 4; ++g) {
                float4 bb = *reinterpret_cast<const float4*>(b1 + t * 32 + g * 8 + hi * 4);
                acc1[g * 4 + 0] = bb.x; acc1[g * 4 + 1] = bb.y;
                acc1[g * 4 + 2] = bb.z; acc1[g * 4 + 3] = bb.w;
            }
            #pragma unroll
            for (int ks = 0; ks < 10; ++ks) {
                short8 wf = *reinterpret_cast<const short8*>(
                    w1s + ((t * 10 + ks) * 64 + lane) * 8);
                acc1 = __builtin_amdgcn_mfma_f32_32x32x16_bf16(wf, fx[ks], acc1, 0, 0, 0);
            }
            // ---- ReLU + bf16 + permlane32_swap -> GEMM2 B-frags in-register ----
            #pragma unroll
            for (int ksl = 0; ksl < 2; ++ksl) {
                int q0 = ksl * 8;
                unsigned D0 = cvt2(fmaxf(acc1[q0 + 0], 0.f), fmaxf(acc1[q0 + 1], 0.f));
                unsigned D1 = cvt2(fmaxf(acc1[q0 + 2], 0.f), fmaxf(acc1[q0 + 3], 0.f));
                unsigned D2 = cvt2(fmaxf(acc1[q0 + 4], 0.f), fmaxf(acc1[q0 + 5], 0.f));
                unsigned D3 = cvt2(fmaxf(acc1[q0 + 6], 0.f), fmaxf(acc1[q0 + 7], 0.f));
                asm volatile("v_permlane32_swap_b32 %0, %1" : "+v"(D0), "+v"(D2));
                asm volatile("v_permlane32_swap_b32 %0, %1" : "+v"(D1), "+v"(D3));
                u32x4 bu; bu[0] = D0; bu[1] = D1; bu[2] = D2; bu[3] = D3;
                short8 hb = __builtin_bit_cast(short8, bu);

                int ks2 = t * 2 + ksl;
                short8 w20 = *reinterpret_cast<const short8*>(w2s + (ks2 * 64 + lane) * 8);
                short8 w21 = *reinterpret_cast<const short8*>(w2s + ((16 + ks2) * 64 + lane) * 8);
                acc2[0] = __builtin_amdgcn_mfma_f32_32x32x16_bf16(w20, hb, acc2[0], 0, 0, 0);
                acc2[1] = __builtin_amdgcn_mfma_f32_32x32x16_bf16(w21, hb, acc2[1], 0, 0, 0);
            }
        }

        // ---- per-edge out store (scattered to original edge id) ----
        #pragma unroll
        for (int t2 = 0; t2 < 2; ++t2)
            #pragma unroll
            for (int g = 0; g < 4; ++g) {
                f32x4 v;
                v[0] = acc2[t2][g * 4 + 0]; v[1] = acc2[t2][g * 4 + 1];
                v[2] = acc2[t2][g * 4 + 2]; v[3] = acc2[t2][g * 4 + 3];
                *reinterpret_cast<f32x4*>(outbuf + (size_t)eo * 64 + t2 * 32 + g * 8 + hi * 4) = v;
            }

        // ---- segmented suffix-max over sorted lanes (destructive on acc2) ----
        unsigned n = (unsigned)r;
        #pragma unroll
        for (int d = 1; d < 32; d <<= 1) {
            unsigned n2 = (unsigned)__shfl_down((int)n, d);
            bool take = ((l32 + d) < 32) && (n2 == n);
            #pragma unroll
            for (int t2 = 0; t2 < 2; ++t2)
                #pragma unroll
                for (int g = 0; g < 16; ++g) {
                    float o = __shfl_down(acc2[t2][g], d);
                    if (take) acc2[t2][g] = fmaxf(acc2[t2][g], o);
                }
        }
        // segment head within chunk -> encoded atomicMax into agg
        unsigned np = (unsigned)__shfl_up((int)n, 1);
        bool headl = (l32 == 0) || (np != n);
        if (headl) {
            unsigned* arow = aggenc + (size_t)n * 64;
            #pragma unroll
            for (int t2 = 0; t2 < 2; ++t2)
                #pragma unroll
                for (int g = 0; g < 4; ++g)
                    #pragma unroll
                    for (int q = 0; q < 4; ++q)
                        atomicMax(&arow[t2 * 32 + g * 8 + hi * 4 + q],
                                  encf(acc2[t2][g * 4 + q]));
        }

        eo = eo_n; r = r_n; cc = cc_n;
    }
}

// decode encoded agg in place: sentinel 0 -> 0.0f (empty node), else inverse map
__global__ void decode_agg(unsigned* __restrict__ agg)
{
    int i = blockIdx.x * 256 + threadIdx.x;
    if (i < NNODES * 64) {
        unsigned u = agg[i];
        float f;
        if (u == 0u)              f = 0.0f;
        else if (u & 0x80000000u) f = __builtin_bit_cast(float, u ^ 0x80000000u);
        else                      f = __builtin_bit_cast(float, ~u);
        reinterpret_cast<float*>(agg)[i] = f;
    }
}

extern "C" void kernel_launch(void* const* d_in, const int* in_sizes, int n_in,
                              void* d_out, int out_size, void* d_ws, size_t ws_size,
                              hipStream_t stream)
{
    const float* x  = (const float*)d_in[0];
    const int*   ei = (const int*)d_in[1];
    const float* ea = (const float*)d_in[2];
    const float* W1 = (const float*)d_in[3];
    const float* b1 = (const float*)d_in[4];
    const float* W2 = (const float*)d_in[5];
    const float* b2 = (const float*)d_in[6];

    float* aggp = (float*)d_out;                          // [N,64] (encoded, then decoded)
    float* outp = aggp + (size_t)NNODES * 64;             // [E,64]

    // ws layout (~10.3 MB, proven size)
    short*    xb   = (short*)d_ws;                        // 6,400,000 B bf16 x
    short*    wpk  = (short*)((char*)d_ws + 6400000);     //   114,688 B packed W1+W2
    unsigned* meta = (unsigned*)((char*)d_ws + 6514688);
    unsigned* cnt   = meta;                               // [50000]
    unsigned* cur   = meta + 50000;                       // [50000]
    unsigned* offs  = meta + 100000;                      // [50001]
    unsigned* bsum  = meta + 150016;                      // [49]
    unsigned* elist = meta + 150144;                      // [800000]

    (void)hipMemsetAsync(cnt, 0, 100000 * sizeof(unsigned), stream);    // cnt + cur
    (void)hipMemsetAsync(aggp, 0, (size_t)NNODES * 64 * 4, stream);     // agg sentinel
    prep_all<<<6410, 256, 0, stream>>>(x, xb, W1, W2, wpk, ei, cnt);
    csr_scan1<<<49, 1024, 0, stream>>>(cnt, offs, bsum);
    csr_scan2<<<1, 64, 0, stream>>>(bsum);
    csr_scan3<<<49, 1024, 0, stream>>>(cnt, offs, bsum);
    csr_place<<<NEDGES / 256, 256, 0, stream>>>(ei, offs, cur, elist);
    edgeconv_main<<<NBLK, 1024, 0, stream>>>(xb, ei, ea, wpk, b1, b2, elist,
                                             outp, (unsigned*)aggp);
    decode_agg<<<(NNODES * 64 + 255) / 256, 256, 0, stream>>>((unsigned*)aggp);
}